// Round 9
// baseline (38.228 us; speedup 1.0000x reference)
//
#include <hip/hip_runtime.h>
#include <stdint.h>

// BLS12-377 Fr: p = 0x12ab655e9a2ca55660b44d1e5c37b00159aa76fed00000010a11800000000001
//
// Reference computes (a*R mod p + b*R mod p) mod p, canonical in [0,p), R = 2^256.
// Inputs a,b each have 4 64-bit limbs < 2^31 (values < 2^223), so a+b < 2^224 < p and
// the result equals (a+b)*R mod p. With s_k = a_k + b_k (< 2^32, no inter-limb carry),
// result = (sum_k s_k * D_k) * 2^-64 mod p where D_k = 2^(320+64k) mod p.
//
// Bounds: T0 = sum s_k*D_k < 2^34*p (9 limbs, limb8 < 2^31).
//   REDC step 1: T1 < 5p < 2^255  (8 limbs, top < 2^31)
//   REDC step 2: T2 < 2p          (single cond_sub -> canonical, bit-exact vs ref)
//
// Harness dtypes: inputs int32[N*4] (limbs < 2^31), output int32[N*4] = low 32 bits
// of each 64-bit output word = even 32-bit limbs of the canonical residue.
//
// Round 9: persistent waves. R8's 34.3us has VALU ~73% / HBM ~58% effective --
// overlap loss from per-wave cold-start load stalls (waves are born in convoys,
// load-stall ~700cyc with nothing to hide it, die after one element). This round:
// grid = 2048 blocks (exactly 8 WG/CU, 32 waves/CU resident), each thread strides
// over 8 elements; next element's loads issue BEFORE current element's ~940-cycle
// mad chain, pinned by an asm memory barrier (loads cannot legally sink below a
// "memory" clobber -- fixes R6 where the compiler sank the prefetch to its use).
// Compute body unchanged from R8 (best: 34.3us, VGPR 16).

#define MASK32 0xffffffffull

namespace {

constexpr uint32_t PL[8] = {
  0x00000001u, 0x0a118000u, 0xd0000001u, 0x59aa76feu,
  0x5c37b001u, 0x60b44d1eu, 0x9a2ca556u, 0x12ab655eu
};

struct U256 { uint32_t l[8]; };

constexpr bool geq_p(const U256& x) {
  for (int i = 7; i >= 0; --i) {
    if (x.l[i] != PL[i]) return x.l[i] > PL[i];
  }
  return true;  // equal
}

// 2^e mod p via double-and-reduce from 2^252 (< p since p > 2^252).
constexpr U256 pow2_mod(int e) {
  U256 x{};
  for (int i = 0; i < 8; ++i) x.l[i] = 0;
  x.l[7] = 0x10000000u;  // 2^252
  for (int it = 0; it < e - 252; ++it) {
    uint32_t carry = 0;
    for (int j = 0; j < 8; ++j) {
      uint32_t nc = x.l[j] >> 31;
      x.l[j] = (x.l[j] << 1) | carry;
      carry = nc;
    }
    if (geq_p(x)) {
      uint64_t borrow = 0;
      for (int j = 0; j < 8; ++j) {
        uint64_t d = (uint64_t)x.l[j] - (uint64_t)PL[j] - borrow;
        x.l[j] = (uint32_t)d;
        borrow = (d >> 32) & 1ull;
      }
    }
  }
  return x;
}

constexpr U256 D0 = pow2_mod(320);
constexpr U256 D1 = pow2_mod(384);
constexpr U256 D2 = pow2_mod(448);
constexpr U256 D3 = pow2_mod(512);

}  // namespace

typedef int v4i __attribute__((ext_vector_type(4)));

__device__ __forceinline__ v4i fr_tomont_add_one(const v4i av, const v4i bv) {
  // s_k = a_k + b_k; input limbs < 2^31 so the 32-bit sum cannot overflow.
  uint32_t s0 = (uint32_t)av.x + (uint32_t)bv.x;
  uint32_t s1 = (uint32_t)av.y + (uint32_t)bv.y;
  uint32_t s2 = (uint32_t)av.z + (uint32_t)bv.z;
  uint32_t s3 = (uint32_t)av.w + (uint32_t)bv.w;

  // All persistent state is 32-bit; x is the only 64-bit temp.
  uint32_t t0, t1, t2, t3, t4, t5, t6, t7, t8;
  uint64_t x;
  uint32_t c;

  // ---- Row 0: t = s0 * D0 ----
  x = (uint64_t)s0 * D0.l[0];            t0 = (uint32_t)x; c = (uint32_t)(x >> 32);
  x = (uint64_t)s0 * D0.l[1] + c;        t1 = (uint32_t)x; c = (uint32_t)(x >> 32);
  x = (uint64_t)s0 * D0.l[2] + c;        t2 = (uint32_t)x; c = (uint32_t)(x >> 32);
  x = (uint64_t)s0 * D0.l[3] + c;        t3 = (uint32_t)x; c = (uint32_t)(x >> 32);
  x = (uint64_t)s0 * D0.l[4] + c;        t4 = (uint32_t)x; c = (uint32_t)(x >> 32);
  x = (uint64_t)s0 * D0.l[5] + c;        t5 = (uint32_t)x; c = (uint32_t)(x >> 32);
  x = (uint64_t)s0 * D0.l[6] + c;        t6 = (uint32_t)x; c = (uint32_t)(x >> 32);
  x = (uint64_t)s0 * D0.l[7] + c;        t7 = (uint32_t)x; t8 = (uint32_t)(x >> 32);

  // ---- Row 1: t += s1 * D1 ----
  x = (uint64_t)s1 * D1.l[0] + t0;       t0 = (uint32_t)x; c = (uint32_t)(x >> 32);
  x = (uint64_t)s1 * D1.l[1] + t1 + c;   t1 = (uint32_t)x; c = (uint32_t)(x >> 32);
  x = (uint64_t)s1 * D1.l[2] + t2 + c;   t2 = (uint32_t)x; c = (uint32_t)(x >> 32);
  x = (uint64_t)s1 * D1.l[3] + t3 + c;   t3 = (uint32_t)x; c = (uint32_t)(x >> 32);
  x = (uint64_t)s1 * D1.l[4] + t4 + c;   t4 = (uint32_t)x; c = (uint32_t)(x >> 32);
  x = (uint64_t)s1 * D1.l[5] + t5 + c;   t5 = (uint32_t)x; c = (uint32_t)(x >> 32);
  x = (uint64_t)s1 * D1.l[6] + t6 + c;   t6 = (uint32_t)x; c = (uint32_t)(x >> 32);
  x = (uint64_t)s1 * D1.l[7] + t7 + c;   t7 = (uint32_t)x; t8 += (uint32_t)(x >> 32);

  // ---- Row 2: t += s2 * D2 ----
  x = (uint64_t)s2 * D2.l[0] + t0;       t0 = (uint32_t)x; c = (uint32_t)(x >> 32);
  x = (uint64_t)s2 * D2.l[1] + t1 + c;   t1 = (uint32_t)x; c = (uint32_t)(x >> 32);
  x = (uint64_t)s2 * D2.l[2] + t2 + c;   t2 = (uint32_t)x; c = (uint32_t)(x >> 32);
  x = (uint64_t)s2 * D2.l[3] + t3 + c;   t3 = (uint32_t)x; c = (uint32_t)(x >> 32);
  x = (uint64_t)s2 * D2.l[4] + t4 + c;   t4 = (uint32_t)x; c = (uint32_t)(x >> 32);
  x = (uint64_t)s2 * D2.l[5] + t5 + c;   t5 = (uint32_t)x; c = (uint32_t)(x >> 32);
  x = (uint64_t)s2 * D2.l[6] + t6 + c;   t6 = (uint32_t)x; c = (uint32_t)(x >> 32);
  x = (uint64_t)s2 * D2.l[7] + t7 + c;   t7 = (uint32_t)x; t8 += (uint32_t)(x >> 32);

  // ---- Row 3: t += s3 * D3 ----
  x = (uint64_t)s3 * D3.l[0] + t0;       t0 = (uint32_t)x; c = (uint32_t)(x >> 32);
  x = (uint64_t)s3 * D3.l[1] + t1 + c;   t1 = (uint32_t)x; c = (uint32_t)(x >> 32);
  x = (uint64_t)s3 * D3.l[2] + t2 + c;   t2 = (uint32_t)x; c = (uint32_t)(x >> 32);
  x = (uint64_t)s3 * D3.l[3] + t3 + c;   t3 = (uint32_t)x; c = (uint32_t)(x >> 32);
  x = (uint64_t)s3 * D3.l[4] + t4 + c;   t4 = (uint32_t)x; c = (uint32_t)(x >> 32);
  x = (uint64_t)s3 * D3.l[5] + t5 + c;   t5 = (uint32_t)x; c = (uint32_t)(x >> 32);
  x = (uint64_t)s3 * D3.l[6] + t6 + c;   t6 = (uint32_t)x; c = (uint32_t)(x >> 32);
  x = (uint64_t)s3 * D3.l[7] + t7 + c;   t7 = (uint32_t)x; t8 += (uint32_t)(x >> 32);

  // ---- REDC step 1 (9 -> 8 limbs): m = -t0 mod 2^32 (p[0] == 1) ----
  {
    uint32_t m = 0u - t0;
    c = (t0 != 0u) ? 1u : 0u;            // carry of t0 + m*1
    x = (uint64_t)m * PL[1] + t1 + c;    t0 = (uint32_t)x; c = (uint32_t)(x >> 32);
    x = (uint64_t)m * PL[2] + t2 + c;    t1 = (uint32_t)x; c = (uint32_t)(x >> 32);
    x = (uint64_t)m * PL[3] + t3 + c;    t2 = (uint32_t)x; c = (uint32_t)(x >> 32);
    x = (uint64_t)m * PL[4] + t4 + c;    t3 = (uint32_t)x; c = (uint32_t)(x >> 32);
    x = (uint64_t)m * PL[5] + t5 + c;    t4 = (uint32_t)x; c = (uint32_t)(x >> 32);
    x = (uint64_t)m * PL[6] + t6 + c;    t5 = (uint32_t)x; c = (uint32_t)(x >> 32);
    x = (uint64_t)m * PL[7] + t7 + c;    t6 = (uint32_t)x; c = (uint32_t)(x >> 32);
    t7 = t8 + c;                          // T1 < 5p < 2^255: no overflow
  }

  // ---- REDC step 2 (8 limbs): T2 < 2p ----
  {
    uint32_t m = 0u - t0;
    c = (t0 != 0u) ? 1u : 0u;
    x = (uint64_t)m * PL[1] + t1 + c;    t0 = (uint32_t)x; c = (uint32_t)(x >> 32);
    x = (uint64_t)m * PL[2] + t2 + c;    t1 = (uint32_t)x; c = (uint32_t)(x >> 32);
    x = (uint64_t)m * PL[3] + t3 + c;    t2 = (uint32_t)x; c = (uint32_t)(x >> 32);
    x = (uint64_t)m * PL[4] + t4 + c;    t3 = (uint32_t)x; c = (uint32_t)(x >> 32);
    x = (uint64_t)m * PL[5] + t5 + c;    t4 = (uint32_t)x; c = (uint32_t)(x >> 32);
    x = (uint64_t)m * PL[6] + t6 + c;    t5 = (uint32_t)x; c = (uint32_t)(x >> 32);
    x = (uint64_t)m * PL[7] + t7 + c;    t6 = (uint32_t)x; t7 = (uint32_t)(x >> 32);
  }

  // ---- cond_sub: T2 < 2p; subtract p iff no borrow -> canonical residue ----
  uint32_t d0, d2, d4, d6;
  uint64_t y;
  y = (uint64_t)t0 - PL[0];                          d0 = (uint32_t)y;
  y = (uint64_t)t1 - PL[1] - ((y >> 32) & 1ull);     /* d1 */
  y = (uint64_t)t2 - PL[2] - ((y >> 32) & 1ull);     d2 = (uint32_t)y;
  y = (uint64_t)t3 - PL[3] - ((y >> 32) & 1ull);     /* d3 */
  y = (uint64_t)t4 - PL[4] - ((y >> 32) & 1ull);     d4 = (uint32_t)y;
  y = (uint64_t)t5 - PL[5] - ((y >> 32) & 1ull);     /* d5 */
  y = (uint64_t)t6 - PL[6] - ((y >> 32) & 1ull);     d6 = (uint32_t)y;
  y = (uint64_t)t7 - PL[7] - ((y >> 32) & 1ull);
  bool use = (((y >> 32) & 1ull) == 0);              // no final borrow -> t >= p
  v4i o;
  o.x = (int)(use ? d0 : t0);
  o.y = (int)(use ? d2 : t2);
  o.z = (int)(use ? d4 : t4);
  o.w = (int)(use ? d6 : t6);
  return o;
}

// Persistent-wave kernel: each thread handles n/stride elements (uniform trip
// count; launcher guarantees n % stride == 0). Next element's loads are pinned
// above the current compute by a compiler memory barrier.
__global__ __launch_bounds__(256) void fr_tomont_add_persistent(
    const v4i* __restrict__ in1,
    const v4i* __restrict__ in2,
    v4i* __restrict__ out,
    int n) {
  int i = blockIdx.x * blockDim.x + threadIdx.x;
  int stride = gridDim.x * blockDim.x;

  v4i a = in1[i];
  v4i b = in2[i];

#pragma unroll 1
  for (;;) {
    int nx = i + stride;
    if (nx >= n) break;
    // Issue next element's loads BEFORE the mad chain.
    v4i an = in1[nx];
    v4i bn = in2[nx];
    // Loads may not sink below a memory-clobber barrier; compute (pure VALU)
    // still schedules freely around it. This pins load-issue early.
    asm volatile("" ::: "memory");
    v4i o = fr_tomont_add_one(a, b);
    __builtin_nontemporal_store(o, out + i);
    i = nx; a = an; b = bn;
  }
  v4i o = fr_tomont_add_one(a, b);
  __builtin_nontemporal_store(o, out + i);
}

// Fallback: one element per thread (R8 structure), for n not divisible by stride.
__global__ __launch_bounds__(256) void fr_tomont_add_kernel(
    const v4i* __restrict__ in1,
    const v4i* __restrict__ in2,
    v4i* __restrict__ out,
    int n) {
  int idx = blockIdx.x * blockDim.x + threadIdx.x;
  if (idx >= n) return;
  v4i o = fr_tomont_add_one(in1[idx], in2[idx]);
  __builtin_nontemporal_store(o, out + idx);
}

extern "C" void kernel_launch(void* const* d_in, const int* in_sizes, int n_in,
                              void* d_out, int out_size, void* d_ws, size_t ws_size,
                              hipStream_t stream) {
  const v4i* in1 = (const v4i*)d_in[0];
  const v4i* in2 = (const v4i*)d_in[1];
  v4i* out = (v4i*)d_out;
  int n = in_sizes[0] / 4;  // (N,4) -> N elements

  const int block = 256;
  const int grid_p = 2048;            // 8 WGs/CU on 256 CUs; 32 waves/CU resident
  const int stride = grid_p * block;  // 524288; N = 4194304 = 8 * stride

  if (n % stride == 0) {
    fr_tomont_add_persistent<<<grid_p, block, 0, stream>>>(in1, in2, out, n);
  } else {
    int grid = (n + block - 1) / block;
    fr_tomont_add_kernel<<<grid, block, 0, stream>>>(in1, in2, out, n);
  }
}

// Round 10
// 36.026 us; speedup vs baseline: 1.0611x; 1.0611x over previous
//
#include <hip/hip_runtime.h>
#include <stdint.h>

// BLS12-377 Fr: p = 0x12ab655e9a2ca55660b44d1e5c37b00159aa76fed00000010a11800000000001
//
// Reference computes (a*R mod p + b*R mod p) mod p, canonical in [0,p), R = 2^256.
// Inputs a,b each have 4 64-bit limbs < 2^31 (values < 2^223), so a+b < 2^224 < p and
// the result equals (a+b)*R mod p. With s_k = a_k + b_k (< 2^32, no inter-limb carry),
// result = (sum_k s_k * D_k) * 2^-64 mod p where D_k = 2^(320+64k) mod p.
//
// Bounds: T0 = sum s_k*D_k < 2^34*p (9 limbs, limb8 < 2^31).
//   REDC step 1: T1 < 5p < 2^255  (8 limbs, top < 2^31)
//   REDC step 2: T2 < 2p          (single cond_sub -> canonical, bit-exact vs ref)
//
// Harness dtypes: inputs int32[N*4] (limbs < 2^31), output int32[N*4] = low 32 bits
// of each 64-bit output word = even 32-bit limbs of the canonical residue.
//
// Round 10: clean 2-chain ILP test on the lean R8 body. Chains A (element idx)
// and B (element idx+half) are interleaved at ROW granularity, tied by zero-cost
// empty-asm pins: asm volatile("" : "+v"(tA0), "+v"(tB0)) forces chain B's row to
// be emitted before the pin and chain A's next row after it (tA0 is re-defined by
// the pin, so its readers must follow), keeping BOTH t-states live across every
// pin -> regalloc must hold both chains (~40 VGPR, tell vs. the serialized 16).
// Unlike R7's sched_barrier(0), nothing else is constrained: the scheduler is
// free to interleave the 16 mads inside each row pair optimally. Zero emitted
// instructions of overhead.

#define MASK32 0xffffffffull
#define PIN(a, b) asm volatile("" : "+v"(a), "+v"(b))

namespace {

constexpr uint32_t PL[8] = {
  0x00000001u, 0x0a118000u, 0xd0000001u, 0x59aa76feu,
  0x5c37b001u, 0x60b44d1eu, 0x9a2ca556u, 0x12ab655eu
};

struct U256 { uint32_t l[8]; };

constexpr bool geq_p(const U256& x) {
  for (int i = 7; i >= 0; --i) {
    if (x.l[i] != PL[i]) return x.l[i] > PL[i];
  }
  return true;  // equal
}

// 2^e mod p via double-and-reduce from 2^252 (< p since p > 2^252).
constexpr U256 pow2_mod(int e) {
  U256 x{};
  for (int i = 0; i < 8; ++i) x.l[i] = 0;
  x.l[7] = 0x10000000u;  // 2^252
  for (int it = 0; it < e - 252; ++it) {
    uint32_t carry = 0;
    for (int j = 0; j < 8; ++j) {
      uint32_t nc = x.l[j] >> 31;
      x.l[j] = (x.l[j] << 1) | carry;
      carry = nc;
    }
    if (geq_p(x)) {
      uint64_t borrow = 0;
      for (int j = 0; j < 8; ++j) {
        uint64_t d = (uint64_t)x.l[j] - (uint64_t)PL[j] - borrow;
        x.l[j] = (uint32_t)d;
        borrow = (d >> 32) & 1ull;
      }
    }
  }
  return x;
}

constexpr U256 D0 = pow2_mod(320);
constexpr U256 D1 = pow2_mod(384);
constexpr U256 D2 = pow2_mod(448);
constexpr U256 D3 = pow2_mod(512);

}  // namespace

typedef int v4i __attribute__((ext_vector_type(4)));

// One full mul-accumulate row: t += s * D (first row: t undefined, init form).
#define ROW_INIT(P, s, D)                                                      \
  x = (uint64_t)(s) * D.l[0];          t##P##0 = (uint32_t)x; c = (uint32_t)(x >> 32); \
  x = (uint64_t)(s) * D.l[1] + c;      t##P##1 = (uint32_t)x; c = (uint32_t)(x >> 32); \
  x = (uint64_t)(s) * D.l[2] + c;      t##P##2 = (uint32_t)x; c = (uint32_t)(x >> 32); \
  x = (uint64_t)(s) * D.l[3] + c;      t##P##3 = (uint32_t)x; c = (uint32_t)(x >> 32); \
  x = (uint64_t)(s) * D.l[4] + c;      t##P##4 = (uint32_t)x; c = (uint32_t)(x >> 32); \
  x = (uint64_t)(s) * D.l[5] + c;      t##P##5 = (uint32_t)x; c = (uint32_t)(x >> 32); \
  x = (uint64_t)(s) * D.l[6] + c;      t##P##6 = (uint32_t)x; c = (uint32_t)(x >> 32); \
  x = (uint64_t)(s) * D.l[7] + c;      t##P##7 = (uint32_t)x; t##P##8 = (uint32_t)(x >> 32)

#define ROW_ACC(P, s, D)                                                       \
  x = (uint64_t)(s) * D.l[0] + t##P##0;     t##P##0 = (uint32_t)x; c = (uint32_t)(x >> 32); \
  x = (uint64_t)(s) * D.l[1] + t##P##1 + c; t##P##1 = (uint32_t)x; c = (uint32_t)(x >> 32); \
  x = (uint64_t)(s) * D.l[2] + t##P##2 + c; t##P##2 = (uint32_t)x; c = (uint32_t)(x >> 32); \
  x = (uint64_t)(s) * D.l[3] + t##P##3 + c; t##P##3 = (uint32_t)x; c = (uint32_t)(x >> 32); \
  x = (uint64_t)(s) * D.l[4] + t##P##4 + c; t##P##4 = (uint32_t)x; c = (uint32_t)(x >> 32); \
  x = (uint64_t)(s) * D.l[5] + t##P##5 + c; t##P##5 = (uint32_t)x; c = (uint32_t)(x >> 32); \
  x = (uint64_t)(s) * D.l[6] + t##P##6 + c; t##P##6 = (uint32_t)x; c = (uint32_t)(x >> 32); \
  x = (uint64_t)(s) * D.l[7] + t##P##7 + c; t##P##7 = (uint32_t)x; t##P##8 += (uint32_t)(x >> 32)

// REDC step dropping one limb: m = -t0 (p[0]==1); shifts t down by one limb.
// LAST=0: t7 = t8 + c (9->8 limbs). LAST=1: t7 = carry (8 limbs, T<2p).
#define REDC1(P)                                                               \
  {                                                                            \
    uint32_t m = 0u - t##P##0;                                                 \
    c = (t##P##0 != 0u) ? 1u : 0u;                                             \
    x = (uint64_t)m * PL[1] + t##P##1 + c; t##P##0 = (uint32_t)x; c = (uint32_t)(x >> 32); \
    x = (uint64_t)m * PL[2] + t##P##2 + c; t##P##1 = (uint32_t)x; c = (uint32_t)(x >> 32); \
    x = (uint64_t)m * PL[3] + t##P##3 + c; t##P##2 = (uint32_t)x; c = (uint32_t)(x >> 32); \
    x = (uint64_t)m * PL[4] + t##P##4 + c; t##P##3 = (uint32_t)x; c = (uint32_t)(x >> 32); \
    x = (uint64_t)m * PL[5] + t##P##5 + c; t##P##4 = (uint32_t)x; c = (uint32_t)(x >> 32); \
    x = (uint64_t)m * PL[6] + t##P##6 + c; t##P##5 = (uint32_t)x; c = (uint32_t)(x >> 32); \
    x = (uint64_t)m * PL[7] + t##P##7 + c; t##P##6 = (uint32_t)x; c = (uint32_t)(x >> 32); \
    t##P##7 = t##P##8 + c;                                                     \
  }

#define REDC2(P)                                                               \
  {                                                                            \
    uint32_t m = 0u - t##P##0;                                                 \
    c = (t##P##0 != 0u) ? 1u : 0u;                                             \
    x = (uint64_t)m * PL[1] + t##P##1 + c; t##P##0 = (uint32_t)x; c = (uint32_t)(x >> 32); \
    x = (uint64_t)m * PL[2] + t##P##2 + c; t##P##1 = (uint32_t)x; c = (uint32_t)(x >> 32); \
    x = (uint64_t)m * PL[3] + t##P##3 + c; t##P##2 = (uint32_t)x; c = (uint32_t)(x >> 32); \
    x = (uint64_t)m * PL[4] + t##P##4 + c; t##P##3 = (uint32_t)x; c = (uint32_t)(x >> 32); \
    x = (uint64_t)m * PL[5] + t##P##5 + c; t##P##4 = (uint32_t)x; c = (uint32_t)(x >> 32); \
    x = (uint64_t)m * PL[6] + t##P##6 + c; t##P##5 = (uint32_t)x; c = (uint32_t)(x >> 32); \
    x = (uint64_t)m * PL[7] + t##P##7 + c; t##P##6 = (uint32_t)x; t##P##7 = (uint32_t)(x >> 32); \
  }

// cond_sub: T < 2p; subtract p iff no final borrow -> canonical; emit even limbs.
#define CONDSUB_OUT(P, ovar)                                                   \
  {                                                                            \
    uint32_t d0, d2, d4, d6;                                                   \
    uint64_t y;                                                                \
    y = (uint64_t)t##P##0 - PL[0];                      d0 = (uint32_t)y;      \
    y = (uint64_t)t##P##1 - PL[1] - ((y >> 32) & 1ull);                        \
    y = (uint64_t)t##P##2 - PL[2] - ((y >> 32) & 1ull); d2 = (uint32_t)y;      \
    y = (uint64_t)t##P##3 - PL[3] - ((y >> 32) & 1ull);                        \
    y = (uint64_t)t##P##4 - PL[4] - ((y >> 32) & 1ull); d4 = (uint32_t)y;      \
    y = (uint64_t)t##P##5 - PL[5] - ((y >> 32) & 1ull);                        \
    y = (uint64_t)t##P##6 - PL[6] - ((y >> 32) & 1ull); d6 = (uint32_t)y;      \
    y = (uint64_t)t##P##7 - PL[7] - ((y >> 32) & 1ull);                        \
    bool use = (((y >> 32) & 1ull) == 0);                                      \
    ovar.x = (int)(use ? d0 : t##P##0);                                        \
    ovar.y = (int)(use ? d2 : t##P##2);                                        \
    ovar.z = (int)(use ? d4 : t##P##4);                                        \
    ovar.w = (int)(use ? d6 : t##P##6);                                        \
  }

__global__ __launch_bounds__(256) void fr_tomont_add_dual(
    const v4i* __restrict__ in1,
    const v4i* __restrict__ in2,
    v4i* __restrict__ out,
    int half) {
  int idx = blockIdx.x * blockDim.x + threadIdx.x;
  if (idx >= half) return;
  int idxB = idx + half;

  v4i avA = in1[idx];
  v4i bvA = in2[idx];
  v4i avB = in1[idxB];
  v4i bvB = in2[idxB];

  uint32_t sA0 = (uint32_t)avA.x + (uint32_t)bvA.x;
  uint32_t sA1 = (uint32_t)avA.y + (uint32_t)bvA.y;
  uint32_t sA2 = (uint32_t)avA.z + (uint32_t)bvA.z;
  uint32_t sA3 = (uint32_t)avA.w + (uint32_t)bvA.w;
  uint32_t sB0 = (uint32_t)avB.x + (uint32_t)bvB.x;
  uint32_t sB1 = (uint32_t)avB.y + (uint32_t)bvB.y;
  uint32_t sB2 = (uint32_t)avB.z + (uint32_t)bvB.z;
  uint32_t sB3 = (uint32_t)avB.w + (uint32_t)bvB.w;

  uint32_t tA0, tA1, tA2, tA3, tA4, tA5, tA6, tA7, tA8;
  uint32_t tB0, tB1, tB2, tB3, tB4, tB5, tB6, tB7, tB8;
  uint64_t x;
  uint32_t c;

  ROW_INIT(A, sA0, D0);
  ROW_INIT(B, sB0, D0);
  PIN(tA0, tB0);
  ROW_ACC(A, sA1, D1);
  ROW_ACC(B, sB1, D1);
  PIN(tA0, tB0);
  ROW_ACC(A, sA2, D2);
  ROW_ACC(B, sB2, D2);
  PIN(tA0, tB0);
  ROW_ACC(A, sA3, D3);
  ROW_ACC(B, sB3, D3);
  PIN(tA0, tB0);
  REDC1(A);
  REDC1(B);
  PIN(tA0, tB0);
  REDC2(A);
  REDC2(B);
  PIN(tA0, tB0);

  v4i oA, oB;
  CONDSUB_OUT(A, oA);
  CONDSUB_OUT(B, oB);
  __builtin_nontemporal_store(oA, out + idx);
  __builtin_nontemporal_store(oB, out + idxB);
}

// Fallback: one element per thread (R8 structure) for odd n.
__global__ __launch_bounds__(256) void fr_tomont_add_single(
    const v4i* __restrict__ in1,
    const v4i* __restrict__ in2,
    v4i* __restrict__ out,
    int n) {
  int idx = blockIdx.x * blockDim.x + threadIdx.x;
  if (idx >= n) return;

  v4i avA = in1[idx];
  v4i bvA = in2[idx];
  uint32_t sA0 = (uint32_t)avA.x + (uint32_t)bvA.x;
  uint32_t sA1 = (uint32_t)avA.y + (uint32_t)bvA.y;
  uint32_t sA2 = (uint32_t)avA.z + (uint32_t)bvA.z;
  uint32_t sA3 = (uint32_t)avA.w + (uint32_t)bvA.w;

  uint32_t tA0, tA1, tA2, tA3, tA4, tA5, tA6, tA7, tA8;
  uint64_t x;
  uint32_t c;

  ROW_INIT(A, sA0, D0);
  ROW_ACC(A, sA1, D1);
  ROW_ACC(A, sA2, D2);
  ROW_ACC(A, sA3, D3);
  REDC1(A);
  REDC2(A);
  v4i oA;
  CONDSUB_OUT(A, oA);
  __builtin_nontemporal_store(oA, out + idx);
}

extern "C" void kernel_launch(void* const* d_in, const int* in_sizes, int n_in,
                              void* d_out, int out_size, void* d_ws, size_t ws_size,
                              hipStream_t stream) {
  const v4i* in1 = (const v4i*)d_in[0];
  const v4i* in2 = (const v4i*)d_in[1];
  v4i* out = (v4i*)d_out;
  int n = in_sizes[0] / 4;  // (N,4) -> N elements

  const int block = 256;
  if ((n & 1) == 0) {
    int half = n / 2;
    int grid = (half + block - 1) / block;
    fr_tomont_add_dual<<<grid, block, 0, stream>>>(in1, in2, out, half);
  } else {
    int grid = (n + block - 1) / block;
    fr_tomont_add_single<<<grid, block, 0, stream>>>(in1, in2, out, n);
  }
}

// Round 11
// 35.121 us; speedup vs baseline: 1.0885x; 1.0258x over previous
//
#include <hip/hip_runtime.h>
#include <stdint.h>

// BLS12-377 Fr: p = 0x12ab655e9a2ca55660b44d1e5c37b00159aa76fed00000010a11800000000001
//
// Reference computes (a*R mod p + b*R mod p) mod p, canonical in [0,p), R = 2^256.
// Inputs a,b each have 4 64-bit limbs < 2^31 (values < 2^223), so a+b < 2^224 < p and
// the result equals (a+b)*R mod p. With s_k = a_k + b_k (< 2^32, no inter-limb carry),
// result = (sum_k s_k * D_k) * 2^-64 mod p where D_k = 2^(320+64k) mod p.
//
// Bounds: T0 = sum s_k*D_k < 2^34*p (9 limbs, limb8 < 2^31).
//   REDC step 1: T1 < 5p < 2^255  (8 limbs, top < 2^31)
//   REDC step 2: T2 < 2p          (single cond_sub -> canonical, bit-exact vs ref)
//
// Harness dtypes: inputs int32[N*4] (limbs < 2^31), output int32[N*4] = low 32 bits
// of each 64-bit output word = even 32-bit limbs of the canonical residue.
//
// Round 11: even/odd product split. R8's serial CIOS puts all 46 mads on one
// carry chain (critical path ~46x mad latency) and spends 2 extra ops/step
// forming the 64-bit {t_j+c} addend. Here each row computes 8 INDEPENDENT
// v_mad_u64_u32:  E_k = s*D_{2k} + t_{2k},  O_k = s*D_{2k+1} + t_{2k+1}
// (no overflow: (2^32-1)^2 + 2^32-1 < 2^64). Even products tile bits [64k,64k+64)
// disjointly, odd products tile [64k+32, ...) disjointly, so one 8-step addc
// chain merges them:
//   limb0=E0.lo, limb1=E0.hi+O0.lo, limb2=E1.lo+O0.hi, ..., limb8=t8+O3.hi.
// REDC steps restructured identically (7 parallel mads + 1 chain). Same mad
// count (46) but parallel dataflow the scheduler cannot serialize, and ~50
// fewer carry-bookkeeping ops. Launch config = R8 (best: 34.3us).

namespace {

constexpr uint32_t PL[8] = {
  0x00000001u, 0x0a118000u, 0xd0000001u, 0x59aa76feu,
  0x5c37b001u, 0x60b44d1eu, 0x9a2ca556u, 0x12ab655eu
};

struct U256 { uint32_t l[8]; };

constexpr bool geq_p(const U256& x) {
  for (int i = 7; i >= 0; --i) {
    if (x.l[i] != PL[i]) return x.l[i] > PL[i];
  }
  return true;  // equal
}

// 2^e mod p via double-and-reduce from 2^252 (< p since p > 2^252).
constexpr U256 pow2_mod(int e) {
  U256 x{};
  for (int i = 0; i < 8; ++i) x.l[i] = 0;
  x.l[7] = 0x10000000u;  // 2^252
  for (int it = 0; it < e - 252; ++it) {
    uint32_t carry = 0;
    for (int j = 0; j < 8; ++j) {
      uint32_t nc = x.l[j] >> 31;
      x.l[j] = (x.l[j] << 1) | carry;
      carry = nc;
    }
    if (geq_p(x)) {
      uint64_t borrow = 0;
      for (int j = 0; j < 8; ++j) {
        uint64_t d = (uint64_t)x.l[j] - (uint64_t)PL[j] - borrow;
        x.l[j] = (uint32_t)d;
        borrow = (d >> 32) & 1ull;
      }
    }
  }
  return x;
}

constexpr U256 D0 = pow2_mod(320);
constexpr U256 D1 = pow2_mod(384);
constexpr U256 D2 = pow2_mod(448);
constexpr U256 D3 = pow2_mod(512);

}  // namespace

typedef int v4i __attribute__((ext_vector_type(4)));

// 32-bit add with carry-in/carry-out; maps to v_add_co_u32 / v_addc_co_u32.
__device__ __forceinline__ uint32_t addc32(uint32_t a, uint32_t b, uint32_t cin,
                                           uint32_t* cout) {
#if __has_builtin(__builtin_addc)
  return __builtin_addc(a, b, cin, cout);
#else
  uint64_t s = (uint64_t)a + b + cin;
  *cout = (uint32_t)(s >> 32);
  return (uint32_t)s;
#endif
}

__global__ __launch_bounds__(256) void fr_tomont_add_kernel(
    const v4i* __restrict__ in1,
    const v4i* __restrict__ in2,
    v4i* __restrict__ out,
    int n) {
  int idx = blockIdx.x * blockDim.x + threadIdx.x;
  if (idx >= n) return;

  v4i av = in1[idx];
  v4i bv = in2[idx];

  // s_k = a_k + b_k; input limbs < 2^31 so the 32-bit sum cannot overflow.
  uint32_t s0 = (uint32_t)av.x + (uint32_t)bv.x;
  uint32_t s1 = (uint32_t)av.y + (uint32_t)bv.y;
  uint32_t s2 = (uint32_t)av.z + (uint32_t)bv.z;
  uint32_t s3 = (uint32_t)av.w + (uint32_t)bv.w;

  uint32_t t0, t1, t2, t3, t4, t5, t6, t7, t8;
  uint32_t cc;

  // ---- Row 0: t = s0 * D0 (8 independent mads, one addc merge chain) ----
  {
    uint64_t E0 = (uint64_t)s0 * D0.l[0];
    uint64_t O0 = (uint64_t)s0 * D0.l[1];
    uint64_t E1 = (uint64_t)s0 * D0.l[2];
    uint64_t O1 = (uint64_t)s0 * D0.l[3];
    uint64_t E2 = (uint64_t)s0 * D0.l[4];
    uint64_t O2 = (uint64_t)s0 * D0.l[5];
    uint64_t E3 = (uint64_t)s0 * D0.l[6];
    uint64_t O3 = (uint64_t)s0 * D0.l[7];
    t0 = (uint32_t)E0;
    t1 = addc32((uint32_t)(E0 >> 32), (uint32_t)O0, 0u, &cc);
    t2 = addc32((uint32_t)E1, (uint32_t)(O0 >> 32), cc, &cc);
    t3 = addc32((uint32_t)(E1 >> 32), (uint32_t)O1, cc, &cc);
    t4 = addc32((uint32_t)E2, (uint32_t)(O1 >> 32), cc, &cc);
    t5 = addc32((uint32_t)(E2 >> 32), (uint32_t)O2, cc, &cc);
    t6 = addc32((uint32_t)E3, (uint32_t)(O2 >> 32), cc, &cc);
    t7 = addc32((uint32_t)(E3 >> 32), (uint32_t)O3, cc, &cc);
    t8 = (uint32_t)(O3 >> 32) + cc;   // < 2^32, no overflow (T < 2^287)
  }

  // ---- Rows 1..3: t += s_r * D_r ----
  // E_k = s*D[2k] + t[2k], O_k = s*D[2k+1] + t[2k+1]; both < 2^64 (no overflow:
  // (2^32-1)^2 + 2^32-1 = 2^64 - 2^33 + 2^32 < 2^64).
#define ROW_ACC(s, D)                                                          \
  {                                                                            \
    uint64_t E0 = (uint64_t)(s) * D.l[0] + t0;                                 \
    uint64_t O0 = (uint64_t)(s) * D.l[1] + t1;                                 \
    uint64_t E1 = (uint64_t)(s) * D.l[2] + t2;                                 \
    uint64_t O1 = (uint64_t)(s) * D.l[3] + t3;                                 \
    uint64_t E2 = (uint64_t)(s) * D.l[4] + t4;                                 \
    uint64_t O2 = (uint64_t)(s) * D.l[5] + t5;                                 \
    uint64_t E3 = (uint64_t)(s) * D.l[6] + t6;                                 \
    uint64_t O3 = (uint64_t)(s) * D.l[7] + t7;                                 \
    t0 = (uint32_t)E0;                                                         \
    t1 = addc32((uint32_t)(E0 >> 32), (uint32_t)O0, 0u, &cc);                  \
    t2 = addc32((uint32_t)E1, (uint32_t)(O0 >> 32), cc, &cc);                  \
    t3 = addc32((uint32_t)(E1 >> 32), (uint32_t)O1, cc, &cc);                  \
    t4 = addc32((uint32_t)E2, (uint32_t)(O1 >> 32), cc, &cc);                  \
    t5 = addc32((uint32_t)(E2 >> 32), (uint32_t)O2, cc, &cc);                  \
    t6 = addc32((uint32_t)E3, (uint32_t)(O2 >> 32), cc, &cc);                  \
    t7 = addc32((uint32_t)(E3 >> 32), (uint32_t)O3, cc, &cc);                  \
    t8 = t8 + (uint32_t)(O3 >> 32) + cc;  /* t8 < 2^31: no overflow */         \
  }

  ROW_ACC(s1, D1);
  ROW_ACC(s2, D2);
  ROW_ACC(s3, D3);
#undef ROW_ACC

  // ---- REDC step 1 (9 -> 8 limbs): m = -t0 mod 2^32 (p[0] == 1) ----
  // T + m*p: limb0 = t0 + m == 0 mod 2^32, carry g = (t0 != 0).
  // E_i = m*p[2i] + t[2i] (i=1..3), O_i = m*p[2i+1] + t[2i+1] (i=0..3).
  // After /2^32: t'_j = limb_{j+1}.
  {
    uint32_t m = 0u - t0;
    uint32_t g = (t0 != 0u) ? 1u : 0u;
    uint64_t O0 = (uint64_t)m * PL[1] + t1;
    uint64_t E1 = (uint64_t)m * PL[2] + t2;
    uint64_t O1 = (uint64_t)m * PL[3] + t3;
    uint64_t E2 = (uint64_t)m * PL[4] + t4;
    uint64_t O2 = (uint64_t)m * PL[5] + t5;
    uint64_t E3 = (uint64_t)m * PL[6] + t6;
    uint64_t O3 = (uint64_t)m * PL[7] + t7;
    t0 = addc32((uint32_t)O0, g, 0u, &cc);                    // limb1
    t1 = addc32((uint32_t)E1, (uint32_t)(O0 >> 32), cc, &cc); // limb2
    t2 = addc32((uint32_t)(E1 >> 32), (uint32_t)O1, cc, &cc); // limb3
    t3 = addc32((uint32_t)E2, (uint32_t)(O1 >> 32), cc, &cc); // limb4
    t4 = addc32((uint32_t)(E2 >> 32), (uint32_t)O2, cc, &cc); // limb5
    t5 = addc32((uint32_t)E3, (uint32_t)(O2 >> 32), cc, &cc); // limb6
    t6 = addc32((uint32_t)(E3 >> 32), (uint32_t)O3, cc, &cc); // limb7
    t7 = t8 + (uint32_t)(O3 >> 32) + cc;  // limb8; T1 < 5p < 2^255: fits 32b
  }

  // ---- REDC step 2 (8 limbs): T2 < 2p ----
  {
    uint32_t m = 0u - t0;
    uint32_t g = (t0 != 0u) ? 1u : 0u;
    uint64_t O0 = (uint64_t)m * PL[1] + t1;
    uint64_t E1 = (uint64_t)m * PL[2] + t2;
    uint64_t O1 = (uint64_t)m * PL[3] + t3;
    uint64_t E2 = (uint64_t)m * PL[4] + t4;
    uint64_t O2 = (uint64_t)m * PL[5] + t5;
    uint64_t E3 = (uint64_t)m * PL[6] + t6;
    uint64_t O3 = (uint64_t)m * PL[7] + t7;
    t0 = addc32((uint32_t)O0, g, 0u, &cc);
    t1 = addc32((uint32_t)E1, (uint32_t)(O0 >> 32), cc, &cc);
    t2 = addc32((uint32_t)(E1 >> 32), (uint32_t)O1, cc, &cc);
    t3 = addc32((uint32_t)E2, (uint32_t)(O1 >> 32), cc, &cc);
    t4 = addc32((uint32_t)(E2 >> 32), (uint32_t)O2, cc, &cc);
    t5 = addc32((uint32_t)E3, (uint32_t)(O2 >> 32), cc, &cc);
    t6 = addc32((uint32_t)(E3 >> 32), (uint32_t)O3, cc, &cc);
    t7 = (uint32_t)(O3 >> 32) + cc;       // T2 < 2p < 2^254: fits 32b
  }

  // ---- cond_sub: T2 < 2p; subtract p iff no final borrow -> canonical ----
  uint32_t d0, d2, d4, d6;
  {
    uint64_t y;
    y = (uint64_t)t0 - PL[0];                          d0 = (uint32_t)y;
    y = (uint64_t)t1 - PL[1] - ((y >> 32) & 1ull);
    y = (uint64_t)t2 - PL[2] - ((y >> 32) & 1ull);     d2 = (uint32_t)y;
    y = (uint64_t)t3 - PL[3] - ((y >> 32) & 1ull);
    y = (uint64_t)t4 - PL[4] - ((y >> 32) & 1ull);     d4 = (uint32_t)y;
    y = (uint64_t)t5 - PL[5] - ((y >> 32) & 1ull);
    y = (uint64_t)t6 - PL[6] - ((y >> 32) & 1ull);     d6 = (uint32_t)y;
    y = (uint64_t)t7 - PL[7] - ((y >> 32) & 1ull);
    bool use = (((y >> 32) & 1ull) == 0);              // no borrow -> t >= p
    v4i o;
    o.x = (int)(use ? d0 : t0);
    o.y = (int)(use ? d2 : t2);
    o.z = (int)(use ? d4 : t4);
    o.w = (int)(use ? d6 : t6);
    __builtin_nontemporal_store(o, out + idx);
  }
}

extern "C" void kernel_launch(void* const* d_in, const int* in_sizes, int n_in,
                              void* d_out, int out_size, void* d_ws, size_t ws_size,
                              hipStream_t stream) {
  const v4i* in1 = (const v4i*)d_in[0];
  const v4i* in2 = (const v4i*)d_in[1];
  v4i* out = (v4i*)d_out;
  int n = in_sizes[0] / 4;  // (N,4) -> N elements

  const int block = 256;
  const int grid = (n + block - 1) / block;
  fr_tomont_add_kernel<<<grid, block, 0, stream>>>(in1, in2, out, n);
}